// Round 1
// baseline (237.741 us; speedup 1.0000x reference)
//
#include <hip/hip_runtime.h>
#include <stdint.h>
#include <math.h>

// RouterLinear: C[b,o] = bias[o] + sum_k W[o, idx[b,k]] * x[b,k]; then top-64
// (values desc, tie -> lower index) per row, outputs vals (f32) then indices
// (written as float values).
//
// Precision strategy: fp32*fp32 products are EXACT in double; accumulate in
// fp64 and keep scores fp64 through top-k so our ranking matches the float64
// numpy reference (index output tolerates essentially no rank swaps).

#define NB    1024
#define NIN   4096
#define NOUT  4096
#define NK    64
#define NTOPK 64
#define OTILE 4   // W rows per block; LDS tile = NIN*OTILE*4B = 64 KB

// ---------------------------------------------------------------- pack ------
// Transpose x/idx from [b][k] to [k][b] so gemm's per-k loads are coalesced.
__global__ __launch_bounds__(256) void pack_kernel(const float* __restrict__ x,
                                                   const int* __restrict__ idx,
                                                   float* __restrict__ xt,
                                                   int* __restrict__ idxt) {
    int tid = blockIdx.x * 256 + threadIdx.x;   // 65536 threads
    int k = tid >> 10;
    int b = tid & 1023;
    idxt[tid] = idx[(b << 6) + k];
    xt[tid]   = x[(b << 6) + k];
}

// ---------------------------------------------------------------- gemm ------
// Block bo owns W rows [bo*4, bo*4+4), staged transposed in LDS as Wt[i][4]
// (16B aligned -> gather is a single ds_read_b128 per nnz). Thread t owns
// b in {4t..4t+3}; acc[4][4] fp64 in registers.
__global__ __launch_bounds__(256) void gemm_kernel(const float* __restrict__ xt,
                                                   const int* __restrict__ idxt,
                                                   const float* __restrict__ W,
                                                   const float* __restrict__ bias,
                                                   double* __restrict__ C) {
    __shared__ float Wt[NIN * OTILE];   // 64 KB
    const int t  = threadIdx.x;
    const int o0 = blockIdx.x * OTILE;

    // Stage 4 rows of W, transposed: Wt[i*4 + r] = W[o0+r][i]
    for (int r = 0; r < OTILE; ++r) {
        const float4* src = reinterpret_cast<const float4*>(W + (size_t)(o0 + r) * NIN);
        for (int j = t; j < NIN / 4; j += 256) {
            float4 v = src[j];
            int i = j << 2;
            Wt[(i + 0) * OTILE + r] = v.x;
            Wt[(i + 1) * OTILE + r] = v.y;
            Wt[(i + 2) * OTILE + r] = v.z;
            Wt[(i + 3) * OTILE + r] = v.w;
        }
    }
    __syncthreads();

    double acc[4][OTILE];
    {
        double bd[OTILE];
        for (int r = 0; r < OTILE; ++r) bd[r] = (double)bias[o0 + r];
        for (int c = 0; c < 4; ++c)
            for (int r = 0; r < OTILE; ++r) acc[c][r] = bd[r];
    }

    const int b0 = t << 2;   // this thread's first b
    for (int k = 0; k < NK; ++k) {
        const int4   iv = *reinterpret_cast<const int4*>(idxt + (k << 10) + b0);
        const float4 xv = *reinterpret_cast<const float4*>(xt  + (k << 10) + b0);
        {
            const float4 w = *reinterpret_cast<const float4*>(Wt + iv.x * OTILE);
            double xd = (double)xv.x;
            acc[0][0] += xd * (double)w.x; acc[0][1] += xd * (double)w.y;
            acc[0][2] += xd * (double)w.z; acc[0][3] += xd * (double)w.w;
        }
        {
            const float4 w = *reinterpret_cast<const float4*>(Wt + iv.y * OTILE);
            double xd = (double)xv.y;
            acc[1][0] += xd * (double)w.x; acc[1][1] += xd * (double)w.y;
            acc[1][2] += xd * (double)w.z; acc[1][3] += xd * (double)w.w;
        }
        {
            const float4 w = *reinterpret_cast<const float4*>(Wt + iv.z * OTILE);
            double xd = (double)xv.z;
            acc[2][0] += xd * (double)w.x; acc[2][1] += xd * (double)w.y;
            acc[2][2] += xd * (double)w.z; acc[2][3] += xd * (double)w.w;
        }
        {
            const float4 w = *reinterpret_cast<const float4*>(Wt + iv.w * OTILE);
            double xd = (double)xv.w;
            acc[3][0] += xd * (double)w.x; acc[3][1] += xd * (double)w.y;
            acc[3][2] += xd * (double)w.z; acc[3][3] += xd * (double)w.w;
        }
    }

    for (int c = 0; c < 4; ++c) {
        double* dst = C + (size_t)(b0 + c) * NOUT + o0;
        dst[0] = acc[c][0]; dst[1] = acc[c][1];
        dst[2] = acc[c][2]; dst[3] = acc[c][3];
    }
}

// ---------------------------------------------------------------- top-k -----
// Monotonic 32-bit key from the high word of a double (order-preserving).
__device__ inline unsigned map_hi(double d) {
    unsigned long long u = (unsigned long long)__double_as_longlong(d);
    unsigned hi = (unsigned)(u >> 32);
    return (hi & 0x80000000u) ? ~hi : (hi | 0x80000000u);
}

// One block per row. 12-bit histogram radix-select of the crossing bin, then
// exact bitonic sort of candidates by (value desc, index asc).
__global__ __launch_bounds__(256) void topk_kernel(const double* __restrict__ C,
                                                   float* __restrict__ outv,
                                                   float* __restrict__ outi) {
    __shared__ double   row[NOUT];     // 32 KB
    __shared__ unsigned hist[4096];    // 16 KB
    __shared__ double   cval[1024];    // 8 KB
    __shared__ int      cidx[1024];    // 4 KB
    __shared__ unsigned part[256];     // 1 KB
    __shared__ int      sBstar;
    __shared__ unsigned sCnt;

    const int t = threadIdx.x;
    const int b = blockIdx.x;

    for (int j = t; j < NOUT; j += 256) row[j] = C[(size_t)b * NOUT + j];
    for (int j = t; j < 4096; j += 256) hist[j] = 0u;
    if (t == 0) sCnt = 0u;
    __syncthreads();

    for (int j = t; j < NOUT; j += 256)
        atomicAdd(&hist[map_hi(row[j]) >> 20], 1u);
    __syncthreads();

    // suffix counts over 256 chunks of 16 bins
    {
        unsigned s = 0;
        for (int q = 0; q < 16; ++q) s += hist[t * 16 + q];
        part[t] = s;
    }
    __syncthreads();
    for (int off = 1; off < 256; off <<= 1) {
        unsigned v = (t + off < 256) ? part[t + off] : 0u;
        __syncthreads();
        part[t] += v;
        __syncthreads();
    }
    // find crossing bin B*: max b with count(key_bin >= b) >= 64
    {
        unsigned run = (t < 255) ? part[t + 1] : 0u;   // cnt_ge((t+1)*16)
        for (int q = 15; q >= 0; --q) {
            int bin = t * 16 + q;
            unsigned cge = run + hist[bin];
            if (cge >= 64u && run < 64u) sBstar = bin;  // exactly one thread/bin hits
            run = cge;
        }
    }
    __syncthreads();

    const unsigned Bstar = (unsigned)sBstar;
    for (int j = t; j < NOUT; j += 256) {
        if ((map_hi(row[j]) >> 20) >= Bstar) {
            unsigned pos = atomicAdd(&sCnt, 1u);
            if (pos < 1024u) { cval[pos] = row[j]; cidx[pos] = j; }
        }
    }
    __syncthreads();

    int M = (int)sCnt; if (M > 1024) M = 1024;   // M >= 64 by construction
    int n = 64; while (n < M) n <<= 1;
    for (int j = M + t; j < n; j += 256) { cval[j] = -INFINITY; cidx[j] = 0x7fffffff; }
    __syncthreads();

    // bitonic sort, order: value desc, index asc
    for (int kk = 2; kk <= n; kk <<= 1) {
        for (int jj = kk >> 1; jj > 0; jj >>= 1) {
            for (int i = t; i < n; i += 256) {
                int l = i ^ jj;
                if (l > i) {
                    double v1 = cval[i], v2 = cval[l];
                    int    i1 = cidx[i], i2 = cidx[l];
                    bool first = (v1 > v2) || (v1 == v2 && i1 < i2);
                    bool asc   = ((i & kk) == 0);
                    if (first != asc) {
                        cval[i] = v2; cval[l] = v1;
                        cidx[i] = i2; cidx[l] = i1;
                    }
                }
            }
            __syncthreads();
        }
    }

    if (t < 64) {
        outv[(b << 6) + t] = (float)cval[t];
        outi[(b << 6) + t] = (float)cidx[t];   // index as numeric float
    }
}

// ---------------------------------------------------------------- launch ----
extern "C" void kernel_launch(void* const* d_in, const int* in_sizes, int n_in,
                              void* d_out, int out_size, void* d_ws, size_t ws_size,
                              hipStream_t stream) {
    const float* x    = (const float*)d_in[0];
    const float* W    = (const float*)d_in[1];
    const float* bias = (const float*)d_in[2];
    const int*   idx  = (const int*)d_in[3];
    // d_in[4] = top_k scalar (always 64 here)

    char*   ws   = (char*)d_ws;
    double* C    = (double*)ws;                                   // 32 MB
    int*    idxt = (int*)(ws + (size_t)NB * NOUT * sizeof(double));        // 256 KB
    float*  xt   = (float*)(ws + (size_t)NB * NOUT * sizeof(double)
                               + (size_t)NB * NK * sizeof(int));           // 256 KB

    float* outv = (float*)d_out;
    float* outi = outv + NB * NTOPK;

    pack_kernel<<<(NB * NK) / 256, 256, 0, stream>>>(x, idx, xt, idxt);
    gemm_kernel<<<NOUT / OTILE, 256, 0, stream>>>(xt, idxt, W, bias, C);
    topk_kernel<<<NB, 256, 0, stream>>>(C, outv, outi);
}

// Round 3
// 174.517 us; speedup vs baseline: 1.3623x; 1.3623x over previous
//
#include <hip/hip_runtime.h>
#include <stdint.h>
#include <math.h>

// RouterLinear: C[b,o] = bias[o] + sum_k W[o, idx[b,k]] * x[b,k]; top-64 per
// row (values desc, tie -> lower index); outputs vals (f32) then indices (as
// float). fp64 accumulation keeps ranking exact vs the float64 np reference.

#define NB    1024
#define NIN   4096
#define NOUT  4096
#define NK    64
#define NTOPK 64
#define OTILE 4   // W rows per block; LDS tile = NIN*OTILE*4B = 64 KB

// ---------------------------------------------------------------- pack ------
__global__ __launch_bounds__(256) void pack_kernel(const float* __restrict__ x,
                                                   const int* __restrict__ idx,
                                                   float* __restrict__ xt,
                                                   int* __restrict__ idxt) {
    int tid = blockIdx.x * 256 + threadIdx.x;   // 65536 threads
    int k = tid >> 10;
    int b = tid & 1023;
    idxt[tid] = idx[(b << 6) + k];
    xt[tid]   = x[(b << 6) + k];
}

// ---------------------------------------------------------------- gemm ------
// Block bo owns W rows [bo*4, bo*4+4), staged transposed in LDS (16B-aligned
// -> gather is one ds_read_b128 per (b,k)). 512 threads (8 waves) x 2
// b-columns each: 2 blocks/CU -> 16 waves/CU for latency hiding.
__global__ __launch_bounds__(512) void gemm_kernel(const float* __restrict__ xt,
                                                   const int* __restrict__ idxt,
                                                   const float* __restrict__ W,
                                                   const float* __restrict__ bias,
                                                   double* __restrict__ C) {
    __shared__ float Wt[NIN * OTILE];   // 64 KB
    const int t  = threadIdx.x;
    const int o0 = blockIdx.x * OTILE;

    for (int r = 0; r < OTILE; ++r) {
        const float4* src = reinterpret_cast<const float4*>(W + (size_t)(o0 + r) * NIN);
        for (int j = t; j < NIN / 4; j += 512) {
            float4 v = src[j];
            int i = j << 2;
            Wt[(i + 0) * OTILE + r] = v.x;
            Wt[(i + 1) * OTILE + r] = v.y;
            Wt[(i + 2) * OTILE + r] = v.z;
            Wt[(i + 3) * OTILE + r] = v.w;
        }
    }
    __syncthreads();

    double acc[2][OTILE];
    for (int r = 0; r < OTILE; ++r) {
        double bd = (double)bias[o0 + r];
        acc[0][r] = bd;
        acc[1][r] = bd;
    }

    const int b0 = t << 1;   // this thread's first b
    const int*   ip = idxt + b0;
    const float* xp = xt + b0;

#pragma unroll 4
    for (int k = 0; k < NK; ++k) {
        const int2   iv = *reinterpret_cast<const int2*>(ip + (k << 10));
        const float2 xv = *reinterpret_cast<const float2*>(xp + (k << 10));
        const float4 w0 = *reinterpret_cast<const float4*>(Wt + iv.x * OTILE);
        const float4 w1 = *reinterpret_cast<const float4*>(Wt + iv.y * OTILE);
        double x0 = (double)xv.x, x1 = (double)xv.y;
        acc[0][0] += x0 * (double)w0.x; acc[0][1] += x0 * (double)w0.y;
        acc[0][2] += x0 * (double)w0.z; acc[0][3] += x0 * (double)w0.w;
        acc[1][0] += x1 * (double)w1.x; acc[1][1] += x1 * (double)w1.y;
        acc[1][2] += x1 * (double)w1.z; acc[1][3] += x1 * (double)w1.w;
    }

    for (int c = 0; c < 2; ++c) {
        double* dst = C + (size_t)(b0 + c) * NOUT + o0;
        dst[0] = acc[c][0]; dst[1] = acc[c][1];
        dst[2] = acc[c][2]; dst[3] = acc[c][3];
    }
}

// ---------------------------------------------------------------- top-k -----
// Monotone fp32 key: rounding double->float preserves order, so selecting all
// elements whose f32-key bin >= the crossing bin yields a superset of the true
// top-64; the exact fp64 sort of candidates then matches np exactly.
__device__ inline unsigned keyf(double d) {
    unsigned u = __float_as_uint((float)d);
    return (u & 0x80000000u) ? ~u : (u | 0x80000000u);
}

__global__ __launch_bounds__(256) void topk_kernel(const double* __restrict__ C,
                                                   float* __restrict__ outv,
                                                   float* __restrict__ outi) {
    __shared__ unsigned hist[4096];    // 16 KB; bin = key>>20 (sign+exp8+mant3)
    __shared__ double   cval[1024];    // 8 KB
    __shared__ int      cidx[1024];    // 4 KB
    __shared__ unsigned part[256];     // 1 KB
    __shared__ int      sBstar;
    __shared__ unsigned sCnt;

    const int t = threadIdx.x;
    const int b = blockIdx.x;
    const double* row = C + (size_t)b * NOUT;

    for (int j = t; j < 4096; j += 256) hist[j] = 0u;
    if (t == 0) sCnt = 0u;
    __syncthreads();

    for (int j = t; j < NOUT; j += 256)
        atomicAdd(&hist[keyf(row[j]) >> 20], 1u);
    __syncthreads();

    // suffix counts over 256 chunks of 16 bins
    {
        unsigned s = 0;
        for (int q = 0; q < 16; ++q) s += hist[t * 16 + q];
        part[t] = s;
    }
    __syncthreads();
    for (int off = 1; off < 256; off <<= 1) {
        unsigned v = (t + off < 256) ? part[t + off] : 0u;
        __syncthreads();
        part[t] += v;
        __syncthreads();
    }
    // crossing bin B*: max bin with count(key_bin >= B*) >= 64
    {
        unsigned run = (t < 255) ? part[t + 1] : 0u;
        for (int q = 15; q >= 0; --q) {
            int bin = t * 16 + q;
            unsigned cge = run + hist[bin];
            if (cge >= 64u && run < 64u) sBstar = bin;
            run = cge;
        }
    }
    __syncthreads();

    const unsigned Bstar = (unsigned)sBstar;
    for (int j = t; j < NOUT; j += 256) {
        double v = row[j];
        if ((keyf(v) >> 20) >= Bstar) {
            unsigned pos = atomicAdd(&sCnt, 1u);
            if (pos < 1024u) { cval[pos] = v; cidx[pos] = j; }
        }
    }
    __syncthreads();

    int M = (int)sCnt; if (M > 1024) M = 1024;
    int n = 64; while (n < M) n <<= 1;
    for (int j = M + t; j < n; j += 256) { cval[j] = -INFINITY; cidx[j] = 0x7fffffff; }
    __syncthreads();

    // bitonic sort: value desc, index asc
    for (int kk = 2; kk <= n; kk <<= 1) {
        for (int jj = kk >> 1; jj > 0; jj >>= 1) {
            for (int i = t; i < n; i += 256) {
                int l = i ^ jj;
                if (l > i) {
                    double v1 = cval[i], v2 = cval[l];
                    int    i1 = cidx[i], i2 = cidx[l];
                    bool first = (v1 > v2) || (v1 == v2 && i1 < i2);
                    bool asc   = ((i & kk) == 0);
                    if (first != asc) {
                        cval[i] = v2; cval[l] = v1;
                        cidx[i] = i2; cidx[l] = i1;
                    }
                }
            }
            __syncthreads();
        }
    }

    if (t < 64) {
        outv[(b << 6) + t] = (float)cval[t];
        outi[(b << 6) + t] = (float)cidx[t];
    }
}

// ---------------------------------------------------------------- launch ----
extern "C" void kernel_launch(void* const* d_in, const int* in_sizes, int n_in,
                              void* d_out, int out_size, void* d_ws, size_t ws_size,
                              hipStream_t stream) {
    const float* x    = (const float*)d_in[0];
    const float* W    = (const float*)d_in[1];
    const float* bias = (const float*)d_in[2];
    const int*   idx  = (const int*)d_in[3];

    char*   ws   = (char*)d_ws;
    double* C    = (double*)ws;                                            // 32 MB
    int*    idxt = (int*)(ws + (size_t)NB * NOUT * sizeof(double));        // 256 KB
    float*  xt   = (float*)(ws + (size_t)NB * NOUT * sizeof(double)
                               + (size_t)NB * NK * sizeof(int));           // 256 KB

    float* outv = (float*)d_out;
    float* outi = outv + NB * NTOPK;

    pack_kernel<<<(NB * NK) / 256, 256, 0, stream>>>(x, idx, xt, idxt);
    gemm_kernel<<<NOUT / OTILE, 512, 0, stream>>>(xt, idxt, W, bias, C);
    topk_kernel<<<NB, 256, 0, stream>>>(C, outv, outi);
}

// Round 4
// 154.166 us; speedup vs baseline: 1.5421x; 1.1320x over previous
//
#include <hip/hip_runtime.h>
#include <stdint.h>
#include <math.h>

// RouterLinear: C[b,o] = bias[o] + sum_k W[o, idx[b,k]] * x[b,k]; top-64 per
// row (values desc, tie -> lower index); outputs vals (f32) then indices (as
// float). fp64 accumulation keeps ranking exact vs the float64 np reference.
//
// R4: staging-write bank conflicts eliminated (in-register 4x4 transpose +
// XOR-swizzled LDS layout: lane j writing i=4j+c spreads evenly over all 8
// bank-groups -> 0 conflicts; R3's strided transpose was 32-way). pack fuses
// (swizzled LDS byte offset, x) so the k-loop is 1 global b128 + 2 LDS b128.

#define NB    1024
#define NIN   4096
#define NOUT  4096
#define NK    64
#define NTOPK 64

__device__ __forceinline__ int SWZ(int i) { return i ^ ((i >> 3) & 7); }

// ---------------------------------------------------------------- pack ------
// fused[k*1024 + b] = { SWZ(idx[b][k])*16 (LDS byte offset), bits(x[b][k]) }
__global__ __launch_bounds__(256) void pack_kernel(const float* __restrict__ x,
                                                   const int* __restrict__ idx,
                                                   int2* __restrict__ fused) {
    int tid = blockIdx.x * 256 + threadIdx.x;   // 65536 threads
    int k = tid >> 10;
    int b = tid & 1023;
    int   iv = idx[(b << 6) + k];
    float xv = x[(b << 6) + k];
    fused[tid] = make_int2(SWZ(iv) << 4, __float_as_int(xv));
}

// ---------------------------------------------------------------- gemm ------
// Block bo owns W rows [bo*4, bo*4+4) in a swizzled-transposed 64 KB LDS tile
// (Wt[SWZ(i)] = column i of the 4 rows). 512 threads (8 waves, 2 blocks/CU),
// 2 b-columns per thread.
__global__ __launch_bounds__(512) void gemm_kernel(const int2* __restrict__ fused,
                                                   const float* __restrict__ W,
                                                   const float* __restrict__ bias,
                                                   double* __restrict__ C) {
    __shared__ float4 Wt[NIN];   // 64 KB
    const int t  = threadIdx.x;
    const int o0 = blockIdx.x * 4;

    // Conflict-free staging: coalesced row loads, 4x4 register transpose,
    // swizzled b128 writes (all 8 bank-groups covered evenly per wave).
    const float4* w0p = reinterpret_cast<const float4*>(W + (size_t)(o0 + 0) * NIN);
    const float4* w1p = reinterpret_cast<const float4*>(W + (size_t)(o0 + 1) * NIN);
    const float4* w2p = reinterpret_cast<const float4*>(W + (size_t)(o0 + 2) * NIN);
    const float4* w3p = reinterpret_cast<const float4*>(W + (size_t)(o0 + 3) * NIN);
#pragma unroll
    for (int m = 0; m < 2; ++m) {
        int j = t + m * 512;          // float4-column index, 0..1023
        float4 r0 = w0p[j], r1 = w1p[j], r2 = w2p[j], r3 = w3p[j];
        int i0 = j << 2;
        Wt[SWZ(i0 + 0)] = make_float4(r0.x, r1.x, r2.x, r3.x);
        Wt[SWZ(i0 + 1)] = make_float4(r0.y, r1.y, r2.y, r3.y);
        Wt[SWZ(i0 + 2)] = make_float4(r0.z, r1.z, r2.z, r3.z);
        Wt[SWZ(i0 + 3)] = make_float4(r0.w, r1.w, r2.w, r3.w);
    }
    __syncthreads();

    double acc[2][4];
    for (int r = 0; r < 4; ++r) {
        double bd = (double)bias[o0 + r];
        acc[0][r] = bd;
        acc[1][r] = bd;
    }

    const int b0 = t << 1;   // this thread's two b's
    const int4* fp = reinterpret_cast<const int4*>(fused + b0);  // {off0,x0,off1,x1}

#pragma unroll 4
    for (int k = 0; k < NK; ++k) {
        int4 f = fp[k * 512];   // element (k*1024 + b0) of fused, as int4
        const float4 w0 = *reinterpret_cast<const float4*>(
            reinterpret_cast<const char*>(Wt) + f.x);
        const float4 w1 = *reinterpret_cast<const float4*>(
            reinterpret_cast<const char*>(Wt) + f.z);
        double x0 = (double)__int_as_float(f.y);
        double x1 = (double)__int_as_float(f.w);
        acc[0][0] += x0 * (double)w0.x; acc[0][1] += x0 * (double)w0.y;
        acc[0][2] += x0 * (double)w0.z; acc[0][3] += x0 * (double)w0.w;
        acc[1][0] += x1 * (double)w1.x; acc[1][1] += x1 * (double)w1.y;
        acc[1][2] += x1 * (double)w1.z; acc[1][3] += x1 * (double)w1.w;
    }

    for (int c = 0; c < 2; ++c) {
        double* dst = C + (size_t)(b0 + c) * NOUT + o0;
        dst[0] = acc[c][0]; dst[1] = acc[c][1];
        dst[2] = acc[c][2]; dst[3] = acc[c][3];
    }
}

// ---------------------------------------------------------------- top-k -----
// Monotone fp32 key: double->float rounding preserves order, so the crossing
// bin over fp32 keys yields a superset of the true top-64; the exact fp64
// bitonic sort of candidates then matches np exactly.
__device__ __forceinline__ unsigned keyf(double d) {
    unsigned u = __float_as_uint((float)d);
    return (u & 0x80000000u) ? ~u : (u | 0x80000000u);
}

__global__ __launch_bounds__(256) void topk_kernel(const double* __restrict__ C,
                                                   float* __restrict__ outv,
                                                   float* __restrict__ outi) {
    __shared__ unsigned hist[4096];    // 16 KB; bin = key>>20 (sign+exp8+mant3)
    __shared__ double   cval[1024];    // 8 KB
    __shared__ int      cidx[1024];    // 4 KB
    __shared__ unsigned part[256];     // 1 KB, chunk sums -> chunk suffixes
    __shared__ int      sBstar;
    __shared__ unsigned sCnt;

    const int t = threadIdx.x;
    const double* row = C + (size_t)blockIdx.x * NOUT;

    // Row into registers once: v[q] = row[q*256 + t] (coalesced).
    double v[16];
#pragma unroll
    for (int q = 0; q < 16; ++q) v[q] = row[q * 256 + t];

    for (int j = t; j < 4096; j += 256) hist[j] = 0u;
    if (t == 0) sCnt = 0u;
    __syncthreads();

#pragma unroll
    for (int q = 0; q < 16; ++q)
        atomicAdd(&hist[keyf(v[q]) >> 20], 1u);
    __syncthreads();

    // chunk sums (16 bins/chunk)
    {
        unsigned s = 0;
        for (int q = 0; q < 16; ++q) s += hist[t * 16 + q];
        part[t] = s;
    }
    __syncthreads();

    // single-wave suffix scan of the 256 chunk sums
    if (t < 64) {
        unsigned c0 = part[4 * t + 0], c1 = part[4 * t + 1];
        unsigned c2 = part[4 * t + 2], c3 = part[4 * t + 3];
        unsigned s = c0 + c1 + c2 + c3;
        unsigned suf = s;
        for (int off = 1; off < 64; off <<= 1) {
            unsigned xx = __shfl_down(suf, off);
            if (t + off < 64) suf += xx;
        }
        unsigned below = suf - s;           // sum of chunks > 4t+3
        part[4 * t + 3] = below + c3;
        part[4 * t + 2] = below + c3 + c2;
        part[4 * t + 1] = below + c3 + c2 + c1;
        part[4 * t + 0] = below + s;
    }
    __syncthreads();

    // crossing bin B*: max bin with count(key_bin >= B*) >= 64
    {
        unsigned run = (t < 255) ? part[t + 1] : 0u;
        for (int q = 15; q >= 0; --q) {
            int bin = t * 16 + q;
            unsigned cge = run + hist[bin];
            if (cge >= 64u && run < 64u) sBstar = bin;
            run = cge;
        }
    }
    __syncthreads();

    const unsigned Bstar = (unsigned)sBstar;
#pragma unroll
    for (int q = 0; q < 16; ++q) {
        if ((keyf(v[q]) >> 20) >= Bstar) {
            unsigned pos = atomicAdd(&sCnt, 1u);
            if (pos < 1024u) { cval[pos] = v[q]; cidx[pos] = q * 256 + t; }
        }
    }
    __syncthreads();

    int M = (int)sCnt; if (M > 1024) M = 1024;
    int n = 64; while (n < M) n <<= 1;
    for (int j = M + t; j < n; j += 256) { cval[j] = -INFINITY; cidx[j] = 0x7fffffff; }
    __syncthreads();

    // bitonic sort: value desc, index asc
    for (int kk = 2; kk <= n; kk <<= 1) {
        for (int jj = kk >> 1; jj > 0; jj >>= 1) {
            for (int i = t; i < n; i += 256) {
                int l = i ^ jj;
                if (l > i) {
                    double v1 = cval[i], v2 = cval[l];
                    int    i1 = cidx[i], i2 = cidx[l];
                    bool first = (v1 > v2) || (v1 == v2 && i1 < i2);
                    bool asc   = ((i & kk) == 0);
                    if (first != asc) {
                        cval[i] = v2; cval[l] = v1;
                        cidx[i] = i2; cidx[l] = i1;
                    }
                }
            }
            __syncthreads();
        }
    }

    if (t < 64) {
        outv[(blockIdx.x << 6) + t] = (float)cval[t];
        outi[(blockIdx.x << 6) + t] = (float)cidx[t];
    }
}

// ---------------------------------------------------------------- launch ----
extern "C" void kernel_launch(void* const* d_in, const int* in_sizes, int n_in,
                              void* d_out, int out_size, void* d_ws, size_t ws_size,
                              hipStream_t stream) {
    const float* x    = (const float*)d_in[0];
    const float* W    = (const float*)d_in[1];
    const float* bias = (const float*)d_in[2];
    const int*   idx  = (const int*)d_in[3];

    char*   ws    = (char*)d_ws;
    double* C     = (double*)ws;                                       // 32 MB
    int2*   fused = (int2*)(ws + (size_t)NB * NOUT * sizeof(double));  // 512 KB

    float* outv = (float*)d_out;
    float* outi = outv + NB * NTOPK;

    pack_kernel<<<(NB * NK) / 256, 256, 0, stream>>>(x, idx, fused);
    gemm_kernel<<<NOUT / 4, 512, 0, stream>>>(fused, W, bias, C);
    topk_kernel<<<NB, 256, 0, stream>>>(C, outv, outi);
}